// Round 6
// baseline (95.094 us; speedup 1.0000x reference)
//
#include <hip/hip_runtime.h>
#include <math.h>

#define BB   4
#define NN   4096
#define DD   128
#define NCLS 5
#define SS   800      // (N - NQ) / NCLS
#define KK   400      // int(0.5 * S)
#define NQ   96
#define MM   (NCLS*KK + NQ)   // 2096
#define NSUP (NCLS*SS)        // 4000

typedef float f4 __attribute__((ext_vector_type(4)));

// ---------------- fused score + top-400 per (b,class) ----------------
// Scores: wave-per-row coalesced loads; f64 expression + shfl_down tree kept
// IDENTICAL in shape to the R2/R3-verified score kernel (absmax 0.0 twice).
// Sort: verified register bitonic (shfl_xor j<64, dbuf LDS j>=64), keys
// (f32 score bits << 32) | (1023 - idx) -> descending score, ascending-index ties.
__global__ void __launch_bounds__(1024)
topk_kernel(const float* __restrict__ X, const float* __restrict__ W,
            const float* __restrict__ bias,
            int* __restrict__ gidx, float* __restrict__ gvals) {
    __shared__ unsigned long long buf[2][1024];
    __shared__ float sS[SS + NQ];          // scores for sup rows (+queries when c==0)
    const int b    = blockIdx.x / NCLS;
    const int c    = blockIdx.x % NCLS;
    const int t    = threadIdx.x;
    const int w    = t >> 6;               // wave id, 16 waves
    const int lane = t & 63;

    const float bias0 = bias[0];
    const double Wd0 = (double)W[lane];
    const double Wd1 = (double)W[lane + 64];

    // 50 sup rows per wave
    for (int r = 0; r < SS / 16; ++r) {
        int lr  = w + 16 * r;              // local row in [0,800)
        const float* x = X + ((size_t)b * NN + c * SS + lr) * DD;
        double acc = (double)x[lane] * Wd0 + (double)x[lane + 64] * Wd1;
        #pragma unroll
        for (int off = 32; off > 0; off >>= 1) acc += __shfl_down(acc, off);
        if (lane == 0) {
            float z32 = (float)acc;
            float u   = (z32 + bias0) / 100.0f;
            float e   = (float)exp(-(double)u);
            sS[lr] = 1.0f / (1.0f + e);
        }
    }
    // 6 query rows per wave (only c==0 blocks use them)
    if (c == 0) {
        for (int r = 0; r < NQ / 16; ++r) {
            int q = w + 16 * r;            // [0,96)
            const float* x = X + ((size_t)b * NN + NSUP + q) * DD;
            double acc = (double)x[lane] * Wd0 + (double)x[lane + 64] * Wd1;
            #pragma unroll
            for (int off = 32; off > 0; off >>= 1) acc += __shfl_down(acc, off);
            if (lane == 0) {
                float z32 = (float)acc;
                float u   = (z32 + bias0) / 100.0f;
                float e   = (float)exp(-(double)u);
                sS[SS + q] = 1.0f / (1.0f + e);
            }
        }
    }
    __syncthreads();

    if (c == 0 && t >= SS && t < SS + NQ) {        // emit queries directly
        int q = t - SS;
        gidx [b * MM + NCLS * KK + q] = NSUP + q;
        gvals[b * MM + NCLS * KK + q] = sS[SS + q];
    }

    unsigned long long v = 0ull;                   // pad sinks
    if (t < SS)
        v = ((unsigned long long)__float_as_uint(sS[t]) << 32) | (unsigned int)(1023 - t);

    int p = 0;
    for (int k = 2; k <= 1024; k <<= 1) {
        for (int j = k >> 1; j > 0; j >>= 1) {
            unsigned long long o;
            if (j >= 64) {
                buf[p][t] = v;
                __syncthreads();
                o = buf[p][t ^ j];
                p ^= 1;   // next reuse of this buffer is 2 stages (1 barrier) away
            } else {
                unsigned int lo = __shfl_xor((unsigned int)(v & 0xFFFFFFFFu), j);
                unsigned int hi = __shfl_xor((unsigned int)(v >> 32), j);
                o = ((unsigned long long)hi << 32) | lo;
            }
            bool keepMax = (((t & k) == 0) == ((t & j) == 0));
            v = keepMax ? (v > o ? v : o) : (v < o ? v : o);
        }
    }

    if (t < KK) {
        int li = 1023 - (int)(v & 0xFFFFFFFFull);
        gidx [b * MM + c * KK + t] = c * SS + li;
        gvals[b * MM + c * KK + t] = __uint_as_float((unsigned int)(v >> 32));
    }
}

// ---------------- fused new_A + new_X + idx: direct-L1 row gather (R3-verified) ----------------
__global__ void __launch_bounds__(256)
newxa_kernel(const float* __restrict__ A, const float* __restrict__ X,
             const int* __restrict__ gidx, const float* __restrict__ gvals,
             float* __restrict__ outA, float* __restrict__ outX, float* __restrict__ outIdx) {
    __shared__ int cidx[MM];
    const int bm = blockIdx.x;            // b*MM + i
    const int b  = bm / MM;
    const int* gb = gidx + b * MM;
    for (int j = threadIdx.x; j < MM; j += 256) cidx[j] = gb[j];
    __syncthreads();

    const int ri = cidx[bm - b * MM];

    if (threadIdx.x < DD) {
        float vscale = gvals[bm];
        float xv = X[((size_t)b * NN + ri) * DD + threadIdx.x] * vscale;
        __builtin_nontemporal_store(xv, outX + (size_t)bm * DD + threadIdx.x);
        if (threadIdx.x == 0) outIdx[bm] = (float)ri;
    }

    const float* arow = A + ((size_t)b * NN + ri) * NN;   // 16 KB row, L1-resident
    float* orow = outA + (size_t)bm * MM;
    for (int jj = threadIdx.x * 4; jj < MM; jj += 1024) {
        f4 vv;
        vv.x = arow[cidx[jj]];
        vv.y = arow[cidx[jj + 1]];
        vv.z = arow[cidx[jj + 2]];
        vv.w = arow[cidx[jj + 3]];
        __builtin_nontemporal_store(vv, (f4*)(orow + jj));
    }
}

extern "C" void kernel_launch(void* const* d_in, const int* in_sizes, int n_in,
                              void* d_out, int out_size, void* d_ws, size_t ws_size,
                              hipStream_t stream) {
    const float* A  = (const float*)d_in[0];
    const float* X  = (const float*)d_in[1];
    const float* W  = (const float*)d_in[2];
    const float* bi = (const float*)d_in[3];

    float* outA   = (float*)d_out;                         // B*M*M
    float* outX   = outA + (size_t)BB * MM * MM;           // B*M*D
    float* outIdx = outX + (size_t)BB * MM * DD;           // B*M

    char* ws = (char*)d_ws;
    int*   gidx  = (int*)  ws;                 // B*M*4 = 33536
    float* gvals = (float*)(ws + 33536);       // B*M*4 = 33536

    topk_kernel<<<BB * NCLS, 1024, 0, stream>>>(X, W, bi, gidx, gvals);
    newxa_kernel<<<BB * MM, 256, 0, stream>>>(A, X, gidx, gvals, outA, outX, outIdx);
}

// Round 7
// 69.539 us; speedup vs baseline: 1.3675x; 1.3675x over previous
//
#include <hip/hip_runtime.h>
#include <math.h>

#define BB   4
#define NN   4096
#define DD   128
#define NCLS 5
#define SS   800      // (N - NQ) / NCLS
#define KK   400      // int(0.5 * S)
#define NQ   96
#define MM   (NCLS*KK + NQ)   // 2096
#define NSUP (NCLS*SS)        // 4000

typedef float f4 __attribute__((ext_vector_type(4)));

// ---------------- scores: f64 dot, exact f32 sigmoid (R2/R3-verified, verbatim) ----------------
__global__ void score_kernel(const float* __restrict__ X, const float* __restrict__ W,
                             const float* __restrict__ bias,
                             float* __restrict__ scoreF) {
    int row  = blockIdx.x * 4 + (threadIdx.x >> 6);   // 4 waves / block
    int lane = threadIdx.x & 63;
    if (row >= BB * NN) return;
    const float* x = X + (size_t)row * DD;
    double acc = (double)x[lane]      * (double)W[lane]
               + (double)x[lane + 64] * (double)W[lane + 64];
    #pragma unroll
    for (int off = 32; off > 0; off >>= 1) acc += __shfl_down(acc, off);
    if (lane == 0) {
        float z32 = (float)acc;
        float u   = (z32 + bias[0]) / 100.0f;
        float e   = (float)exp(-(double)u);
        float t   = 1.0f + e;
        float s   = 1.0f / t;
        scoreF[row] = s;
    }
}

// ---------------- top-400 per (b,class): register bitonic (R3-verified, verbatim) ----------------
__global__ void __launch_bounds__(1024)
topk_kernel(const float* __restrict__ scoreF, int* __restrict__ gidx, float* __restrict__ gvals) {
    __shared__ unsigned long long buf[2][1024];
    const int b = blockIdx.x / NCLS;
    const int c = blockIdx.x % NCLS;
    const int t = threadIdx.x;

    if (c == 0 && t >= 512 && t < 512 + NQ) {
        int q  = t - 512;
        int gi = NSUP + q;
        int m  = NCLS * KK + q;
        gidx [b * MM + m] = gi;
        gvals[b * MM + m] = scoreF[(size_t)b * NN + gi];
    }

    const float* sc = scoreF + (size_t)b * NN + c * SS;
    unsigned long long v = 0ull;    // pad sinks
    if (t < SS)
        v = ((unsigned long long)__float_as_uint(sc[t]) << 32) | (unsigned int)(1023 - t);

    int p = 0;
    for (int k = 2; k <= 1024; k <<= 1) {
        for (int j = k >> 1; j > 0; j >>= 1) {
            unsigned long long o;
            if (j >= 64) {
                buf[p][t] = v;
                __syncthreads();
                o = buf[p][t ^ j];
                p ^= 1;   // next reuse of this buffer is 2 stages (1 barrier) away
            } else {
                unsigned int lo = __shfl_xor((unsigned int)(v & 0xFFFFFFFFu), j);
                unsigned int hi = __shfl_xor((unsigned int)(v >> 32), j);
                o = ((unsigned long long)hi << 32) | lo;
            }
            bool keepMax = (((t & k) == 0) == ((t & j) == 0));
            v = keepMax ? (v > o ? v : o) : (v < o ? v : o);
        }
    }

    if (t < KK) {
        int li = 1023 - (int)(v & 0xFFFFFFFFull);
        gidx [b * MM + c * KK + t] = c * SS + li;
        gvals[b * MM + c * KK + t] = __uint_as_float((unsigned int)(v >> 32));
    }
}

// ---------------- fused new_A + new_X + idx: direct-L1 gather + coalesced row prefetch ----------------
// Change vs R3-verified newa: (a) coalesced register prefetch of the 16KB A-row so HBM
// sees streaming order and the random gathers hit L1/L2; (b) newx/idx fused in (R5-safe).
// Stores are PLAIN (nt reverted — unattributed R6 regression suspect).
__global__ void __launch_bounds__(256)
newxa_kernel(const float* __restrict__ A, const float* __restrict__ X,
             const int* __restrict__ gidx, const float* __restrict__ gvals,
             float* __restrict__ outA, float* __restrict__ outX, float* __restrict__ outIdx) {
    __shared__ int cidx[MM];
    const int bm = blockIdx.x;            // b*MM + i
    const int b  = bm / MM;

    // row index for this block: single broadcast load (gidx is L2-hot, 33 KB)
    const int ri = gidx[bm];

    // issue coalesced streaming prefetch of the whole A row ASAP (read-once in HBM order)
    const f4* arow4 = (const f4*)(A + ((size_t)b * NN + ri) * NN);
    f4 pf0 = arow4[              threadIdx.x];
    f4 pf1 = arow4[256 +         threadIdx.x];
    f4 pf2 = arow4[512 +         threadIdx.x];
    f4 pf3 = arow4[768 +         threadIdx.x];
    asm volatile("" :: "v"(pf0), "v"(pf1), "v"(pf2), "v"(pf3));   // keep loads live, data lands in L1/L2

    // cidx fill overlaps the prefetch latency
    const int* gb = gidx + b * MM;
    for (int j = threadIdx.x; j < MM; j += 256) cidx[j] = gb[j];

    if (threadIdx.x < DD) {
        float vscale = gvals[bm];
        outX[(size_t)bm * DD + threadIdx.x] =
            X[((size_t)b * NN + ri) * DD + threadIdx.x] * vscale;
        if (threadIdx.x == 0) outIdx[bm] = (float)ri;
    }
    __syncthreads();

    // random gathers now hit cache; writes coalesced float4 (MM = 4*524)
    const float* arow = (const float*)arow4;
    float* orow = outA + (size_t)bm * MM;
    for (int jj = threadIdx.x * 4; jj < MM; jj += 1024) {
        f4 vv;
        vv.x = arow[cidx[jj]];
        vv.y = arow[cidx[jj + 1]];
        vv.z = arow[cidx[jj + 2]];
        vv.w = arow[cidx[jj + 3]];
        *(f4*)(orow + jj) = vv;
    }
}

extern "C" void kernel_launch(void* const* d_in, const int* in_sizes, int n_in,
                              void* d_out, int out_size, void* d_ws, size_t ws_size,
                              hipStream_t stream) {
    const float* A  = (const float*)d_in[0];
    const float* X  = (const float*)d_in[1];
    const float* W  = (const float*)d_in[2];
    const float* bi = (const float*)d_in[3];

    float* outA   = (float*)d_out;                         // B*M*M
    float* outX   = outA + (size_t)BB * MM * MM;           // B*M*D
    float* outIdx = outX + (size_t)BB * MM * DD;           // B*M

    char* ws = (char*)d_ws;
    float* scoreF = (float*)ws;                                 // B*N*4 = 65536
    int*   gidx   = (int*)  (ws + 65536);                       // B*M*4 = 33536
    float* gvals  = (float*)(ws + 65536 + 33536);               // B*M*4 = 33536

    score_kernel<<<(BB * NN) / 4, 256, 0, stream>>>(X, W, bi, scoreF);
    topk_kernel<<<BB * NCLS, 1024, 0, stream>>>(scoreF, gidx, gvals);
    newxa_kernel<<<BB * MM, 256, 0, stream>>>(A, X, gidx, gvals, outA, outX, outIdx);
}

// Round 8
// 59.100 us; speedup vs baseline: 1.6090x; 1.1766x over previous
//
#include <hip/hip_runtime.h>
#include <math.h>

#define BB   4
#define NN   4096
#define DD   128
#define NCLS 5
#define SS   800      // (N - NQ) / NCLS
#define KK   400      // int(0.5 * S)
#define NQ   96
#define MM   (NCLS*KK + NQ)   // 2096
#define NSUP (NCLS*SS)        // 4000

typedef float f4 __attribute__((ext_vector_type(4)));

// ---------------- scores: f64 dot, exact f32 sigmoid (R2/R3-verified, verbatim) ----------------
__global__ void score_kernel(const float* __restrict__ X, const float* __restrict__ W,
                             const float* __restrict__ bias,
                             float* __restrict__ scoreF) {
    int row  = blockIdx.x * 4 + (threadIdx.x >> 6);   // 4 waves / block
    int lane = threadIdx.x & 63;
    if (row >= BB * NN) return;
    const float* x = X + (size_t)row * DD;
    double acc = (double)x[lane]      * (double)W[lane]
               + (double)x[lane + 64] * (double)W[lane + 64];
    #pragma unroll
    for (int off = 32; off > 0; off >>= 1) acc += __shfl_down(acc, off);
    if (lane == 0) {
        float z32 = (float)acc;
        float u   = (z32 + bias[0]) / 100.0f;
        float e   = (float)exp(-(double)u);
        float t   = 1.0f + e;
        float s   = 1.0f / t;
        scoreF[row] = s;
    }
}

// ---------------- top-400 per (b,class): register bitonic (R3-verified, verbatim) ----------------
__global__ void __launch_bounds__(1024)
topk_kernel(const float* __restrict__ scoreF, int* __restrict__ gidx, float* __restrict__ gvals) {
    __shared__ unsigned long long buf[2][1024];
    const int b = blockIdx.x / NCLS;
    const int c = blockIdx.x % NCLS;
    const int t = threadIdx.x;

    if (c == 0 && t >= 512 && t < 512 + NQ) {
        int q  = t - 512;
        int gi = NSUP + q;
        int m  = NCLS * KK + q;
        gidx [b * MM + m] = gi;
        gvals[b * MM + m] = scoreF[(size_t)b * NN + gi];
    }

    const float* sc = scoreF + (size_t)b * NN + c * SS;
    unsigned long long v = 0ull;    // pad sinks
    if (t < SS)
        v = ((unsigned long long)__float_as_uint(sc[t]) << 32) | (unsigned int)(1023 - t);

    int p = 0;
    for (int k = 2; k <= 1024; k <<= 1) {
        for (int j = k >> 1; j > 0; j >>= 1) {
            unsigned long long o;
            if (j >= 64) {
                buf[p][t] = v;
                __syncthreads();
                o = buf[p][t ^ j];
                p ^= 1;   // next reuse of this buffer is 2 stages (1 barrier) away
            } else {
                unsigned int lo = __shfl_xor((unsigned int)(v & 0xFFFFFFFFu), j);
                unsigned int hi = __shfl_xor((unsigned int)(v >> 32), j);
                o = ((unsigned long long)hi << 32) | lo;
            }
            bool keepMax = (((t & k) == 0) == ((t & j) == 0));
            v = keepMax ? (v > o ? v : o) : (v < o ? v : o);
        }
    }

    if (t < KK) {
        int li = 1023 - (int)(v & 0xFFFFFFFFull);
        gidx [b * MM + c * KK + t] = c * SS + li;
        gvals[b * MM + c * KK + t] = __uint_as_float((unsigned int)(v >> 32));
    }
}

// ---------------- fused new_A + new_X + idx: HBM->LDS async staging, LDS gather ----------------
// Single change vs R3-verified newxa: A-row staged via global_load_lds (width=16,
// linear LDS dest = wave-uniform base + lane*16) -> HBM sees pure streaming order,
// gathers hit LDS instead of thrashing L1 (8 blocks/CU x 16KB rows > 32KB L1).
__global__ void __launch_bounds__(256)
newxa_kernel(const float* __restrict__ A, const float* __restrict__ X,
             const int* __restrict__ gidx, const float* __restrict__ gvals,
             float* __restrict__ outA, float* __restrict__ outX, float* __restrict__ outIdx) {
    __shared__ int   cidx[MM];
    __shared__ float rowA[NN];
    const int bm = blockIdx.x;            // b*MM + i
    const int b  = bm / MM;
    const int ri = gidx[bm];              // broadcast scalar load (gidx L2-hot)

    // async stage: 16 instructions copy 4096 floats; instr s copies 1KB at
    // rowA[base..base+255] from arow[base + lane*4 ..], base wave-uniform.
    {
        const float* arow = A + ((size_t)b * NN + ri) * NN;
        const int wv = threadIdx.x >> 6, ln = threadIdx.x & 63;
        #pragma unroll
        for (int sgm = 0; sgm < 4; ++sgm) {
            int base = (wv * 4 + sgm) * 256;               // float offset, wave-uniform
            const float* gsrc = arow + base + ln * 4;      // per-lane global addr
            float*       ldst = rowA + base;               // wave-uniform LDS base
            __builtin_amdgcn_global_load_lds(
                (__attribute__((address_space(1))) void*)(const_cast<float*>(gsrc)),
                (__attribute__((address_space(3))) void*)(ldst),
                16, 0, 0);
        }
    }

    // cidx fill + newX overlap the staging latency
    const int* gb = gidx + b * MM;
    for (int j = threadIdx.x; j < MM; j += 256) cidx[j] = gb[j];

    if (threadIdx.x < DD) {
        float vscale = gvals[bm];
        outX[(size_t)bm * DD + threadIdx.x] =
            X[((size_t)b * NN + ri) * DD + threadIdx.x] * vscale;
        if (threadIdx.x == 0) outIdx[bm] = (float)ri;
    }
    __syncthreads();   // drains vmcnt (global_load_lds) + lgkmcnt (cidx writes)

    // gather from LDS (random banks ~2-way, free), coalesced f4 stores (MM = 4*524)
    float* orow = outA + (size_t)bm * MM;
    for (int jj = threadIdx.x * 4; jj < MM; jj += 1024) {
        f4 vv;
        vv.x = rowA[cidx[jj]];
        vv.y = rowA[cidx[jj + 1]];
        vv.z = rowA[cidx[jj + 2]];
        vv.w = rowA[cidx[jj + 3]];
        *(f4*)(orow + jj) = vv;
    }
}

extern "C" void kernel_launch(void* const* d_in, const int* in_sizes, int n_in,
                              void* d_out, int out_size, void* d_ws, size_t ws_size,
                              hipStream_t stream) {
    const float* A  = (const float*)d_in[0];
    const float* X  = (const float*)d_in[1];
    const float* W  = (const float*)d_in[2];
    const float* bi = (const float*)d_in[3];

    float* outA   = (float*)d_out;                         // B*M*M
    float* outX   = outA + (size_t)BB * MM * MM;           // B*M*D
    float* outIdx = outX + (size_t)BB * MM * DD;           // B*M

    char* ws = (char*)d_ws;
    float* scoreF = (float*)ws;                                 // B*N*4 = 65536
    int*   gidx   = (int*)  (ws + 65536);                       // B*M*4 = 33536
    float* gvals  = (float*)(ws + 65536 + 33536);               // B*M*4 = 33536

    score_kernel<<<(BB * NN) / 4, 256, 0, stream>>>(X, W, bi, scoreF);
    topk_kernel<<<BB * NCLS, 1024, 0, stream>>>(scoreF, gidx, gvals);
    newxa_kernel<<<BB * MM, 256, 0, stream>>>(A, X, gidx, gvals, outA, outX, outIdx);
}